// Round 5
// baseline (698.862 us; speedup 1.0000x reference)
//
#include <hip/hip_runtime.h>
#include <hip/hip_bf16.h>

#define N_ 65536
#define D_ 768
#define L_ 100
#define B_ 8192
#define NTILES 6     // D_/128 column tiles in gemm_pooled
#define MAXBAG 64    // per-wave logit scratch (bags are ~Poisson(8); max ~30)

typedef __attribute__((ext_vector_type(8))) short short8;
typedef __attribute__((ext_vector_type(4))) float floatx4;

__device__ __forceinline__ unsigned short f2bf(float f) {
    unsigned int u = __float_as_uint(f);
    u += 0x7fff + ((u >> 16) & 1);   // RNE
    return (unsigned short)(u >> 16);
}
__device__ __forceinline__ float bf2f(unsigned short u) {
    return __uint_as_float(((unsigned int)u) << 16);
}
// pack 2 f32 -> 2 bf16 (RNE) — v_cvt_pk_bf16_f32 on gfx950
__device__ __forceinline__ unsigned int cvt2(float lo, float hi) {
    __hip_bfloat162 r = __float22bfloat162_rn(float2{lo, hi});
    return *reinterpret_cast<unsigned int*>(&r);
}

// async global->LDS, 16B per lane; lds dest is wave-uniform base + lane*16
__device__ __forceinline__ void gload16(const unsigned short* g, unsigned short* l) {
    __builtin_amdgcn_global_load_lds(
        (const __attribute__((address_space(1))) void*)g,
        (__attribute__((address_space(3))) void*)l, 16, 0, 0);
}

// ---- prep: Wt (transpose W_fc -> [n][k] bf16), Wct (transpose+pad W_cls) ----
#define WT_BLK    ((D_ * D_ + 255) / 256)      // 2304
#define WCT_BLK   ((128 * D_ + 255) / 256)     // 384
__global__ __launch_bounds__(256) void prep_kernel(
    const float* __restrict__ Wfc, unsigned short* __restrict__ Wt,
    const float* __restrict__ Wcls, unsigned short* __restrict__ Wct)
{
    int bid = blockIdx.x;
    if (bid < WT_BLK) {
        int t = bid * 256 + threadIdx.x;
        if (t < D_ * D_) {
            int n = t / D_, k = t % D_;
            Wt[t] = f2bf(Wfc[k * D_ + n]);
        }
    } else {
        int t = (bid - WT_BLK) * 256 + threadIdx.x;
        if (t < 128 * D_) {
            int n = t / D_, k = t % D_;
            Wct[t] = (n < L_) ? f2bf(Wcls[k * L_ + n]) : (unsigned short)0;
        }
    }
}

// ---- pooled = h(f32) @ W_fc + b_fc -----------------------------------------
// Barrier-free: NO LDS. Each wave loads A fragments directly from f32 h
// (inline cvt to bf16) and B fragments directly from bf16 Wt (L2-resident).
__global__ __launch_bounds__(256) void gemm_pooled(
    const float* __restrict__ H,            // h f32 [N][768]
    const unsigned short* __restrict__ Bt,  // Wt bf16 [768(n)][768(k)]
    const float* __restrict__ bias,         // b_fc
    unsigned short* __restrict__ P)         // pooled bf16 [N][768]
{
    const int tid  = threadIdx.x;
    const int lane = tid & 63;
    const int l15  = lane & 15;
    const int quad = lane >> 4;
    const int wave = tid >> 6;
    const int wm   = wave >> 1, wn = wave & 1;

    // XCD-aware swizzle: a row-tile's NTILES col-blocks stay on one XCD
    const int bid  = blockIdx.x;          // 3072 blocks
    const int xcd  = bid & 7;
    const int j    = bid >> 3;
    const int colt = j % NTILES;
    const int rowt = xcd + (j / NTILES) * 8;
    const size_t mBase = (size_t)rowt * 128;
    const size_t nBase = (size_t)colt * 128;

    // A fragment sources: f32 row (mBase + wm*64 + mi*16 + l15), cols quad*8+...
    const float* aRow[4];
#pragma unroll
    for (int mi = 0; mi < 4; ++mi)
        aRow[mi] = H + (mBase + wm * 64 + mi * 16 + l15) * D_ + quad * 8;
    // B fragment sources: bf16 row (nBase + wn*64 + ni*16 + l15)
    const unsigned short* bRow[4];
#pragma unroll
    for (int ni = 0; ni < 4; ++ni)
        bRow[ni] = Bt + (nBase + wn * 64 + ni * 16 + l15) * D_ + quad * 8;

    floatx4 acc[4][4];
#pragma unroll
    for (int mi = 0; mi < 4; ++mi)
#pragma unroll
        for (int ni = 0; ni < 4; ++ni) acc[mi][ni] = (floatx4){0.f, 0.f, 0.f, 0.f};

#pragma unroll 2
    for (int k0 = 0; k0 < D_; k0 += 32) {
        short8 af[4], bf[4];
#pragma unroll
        for (int mi = 0; mi < 4; ++mi) {
            float4 a0 = *(const float4*)(aRow[mi] + k0);
            float4 a1 = *(const float4*)(aRow[mi] + k0 + 4);
            uint4 o;
            o.x = cvt2(a0.x, a0.y); o.y = cvt2(a0.z, a0.w);
            o.z = cvt2(a1.x, a1.y); o.w = cvt2(a1.z, a1.w);
            af[mi] = *reinterpret_cast<short8*>(&o);
        }
#pragma unroll
        for (int ni = 0; ni < 4; ++ni)
            bf[ni] = *(const short8*)(bRow[ni] + k0);
#pragma unroll
        for (int mi = 0; mi < 4; ++mi)
#pragma unroll
            for (int ni = 0; ni < 4; ++ni)
                acc[mi][ni] = __builtin_amdgcn_mfma_f32_16x16x32_bf16(
                    af[mi], bf[ni], acc[mi][ni], 0, 0, 0);
    }
    // C/D: col = lane&15, row = quad*4 + reg
#pragma unroll
    for (int ni = 0; ni < 4; ++ni) {
        int col = (int)nBase + wn * 64 + ni * 16 + l15;
        float bv = bias[col];
#pragma unroll
        for (int mi = 0; mi < 4; ++mi)
#pragma unroll
            for (int r = 0; r < 4; ++r) {
                size_t row = mBase + wm * 64 + mi * 16 + quad * 4 + r;
                P[row * D_ + col] = f2bf(acc[mi][ni][r] + bv);
            }
    }
}

// ---- logits = bag_repre(bf16) @ Wct^T + b_cls -------------------------------
__global__ __launch_bounds__(256) void gemm_cls(
    const unsigned short* __restrict__ A,   // repre bf16 [B_][768]
    const unsigned short* __restrict__ Bt,  // Wct bf16 [128][768]
    const float* __restrict__ bias,         // b_cls [100]
    float* __restrict__ out)                // [B_][100] f32
{
    __shared__ __align__(16) unsigned short As[128 * 32];
    __shared__ __align__(16) unsigned short Bs[128 * 32];
    const int tid  = threadIdx.x;
    const int lane = tid & 63;
    const int wave = tid >> 6;
    const int l15  = lane & 15;
    const int quad = lane >> 4;
    const int wm   = wave >> 1, wn = wave & 1;
    const size_t mBase = (size_t)blockIdx.x * 128;

    const int c0 = wave * 128 + lane;
    const int c1 = c0 + 64;
    const int r0 = c0 >> 2, s0 = (c0 & 3) * 8;
    const int r1 = c1 >> 2, s1 = (c1 & 3) * 8;
    unsigned short* ldsA0 = As + wave * 1024;
    unsigned short* ldsA1 = As + wave * 1024 + 512;
    unsigned short* ldsB0 = Bs + wave * 1024;
    unsigned short* ldsB1 = Bs + wave * 1024 + 512;
    const unsigned short* gA0 = A  + (mBase + r0) * D_ + s0;
    const unsigned short* gA1 = A  + (mBase + r1) * D_ + s1;
    const unsigned short* gB0 = Bt + (size_t)r0 * D_ + s0;
    const unsigned short* gB1 = Bt + (size_t)r1 * D_ + s1;

    floatx4 acc[4][4];
#pragma unroll
    for (int mi = 0; mi < 4; ++mi)
#pragma unroll
        for (int ni = 0; ni < 4; ++ni) acc[mi][ni] = (floatx4){0.f, 0.f, 0.f, 0.f};

    for (int k0 = 0; k0 < D_; k0 += 32) {
        __syncthreads();
        gload16(gA0 + k0, ldsA0);
        gload16(gA1 + k0, ldsA1);
        gload16(gB0 + k0, ldsB0);
        gload16(gB1 + k0, ldsB1);
        __syncthreads();
        short8 af[4], bfr[4];
#pragma unroll
        for (int mi = 0; mi < 4; ++mi)
            af[mi] = *(const short8*)&As[(wm * 64 + mi * 16 + l15) * 32 + quad * 8];
#pragma unroll
        for (int ni = 0; ni < 4; ++ni)
            bfr[ni] = *(const short8*)&Bs[(wn * 64 + ni * 16 + l15) * 32 + quad * 8];
#pragma unroll
        for (int mi = 0; mi < 4; ++mi)
#pragma unroll
            for (int ni = 0; ni < 4; ++ni)
                acc[mi][ni] = __builtin_amdgcn_mfma_f32_16x16x32_bf16(
                    af[mi], bfr[ni], acc[mi][ni], 0, 0, 0);
    }
#pragma unroll
    for (int ni = 0; ni < 4; ++ni) {
        int col = wn * 64 + ni * 16 + l15;
        if (col < L_) {
            float bvv = bias[col];
#pragma unroll
            for (int mi = 0; mi < 4; ++mi)
#pragma unroll
                for (int r = 0; r < 4; ++r) {
                    size_t row = mBase + wm * 64 + mi * 16 + quad * 4 + r;
                    out[row * L_ + col] = acc[mi][ni][r] + bvv;
                }
        }
    }
}

__device__ __forceinline__ int lower_bound_seg(const int* __restrict__ seg, int key) {
    int lo = 0, hi = N_;
    while (lo < hi) {
        int mid = (lo + hi) >> 1;
        if (seg[mid] < key) lo = mid + 1; else hi = mid;
    }
    return lo;
}

// full-wave dot of pooled row i with att[q]; every lane returns the dot
__device__ __forceinline__ float row_logit(
    const unsigned short* __restrict__ P, const float* __restrict__ att,
    int i, int q, int lane)
{
    const ushort4* pr = (const ushort4*)(P + (size_t)i * D_);
    const float4*  ar = (const float4*)(att + (size_t)q * D_);
    float d = 0.f;
#pragma unroll
    for (int jj = 0; jj < 3; ++jj) {
        ushort4 v = pr[lane + jj * 64];
        float4  a = ar[lane + jj * 64];
        d += bf2f(v.x) * a.x + bf2f(v.y) * a.y + bf2f(v.z) * a.z + bf2f(v.w) * a.w;
    }
#pragma unroll
    for (int off = 32; off > 0; off >>= 1) d += __shfl_xor(d, off, 64);
    return d;   // identical on all 64 lanes
}

// ---- per-bag: logits + softmax + weighted sum, one wave per bag -------------
__global__ __launch_bounds__(256) void bag_kernel(
    const unsigned short* __restrict__ P, const float* __restrict__ att,
    const int* __restrict__ query, const int* __restrict__ seg,
    unsigned short* __restrict__ R)
{
    __shared__ float scratch[4][MAXBAG];
    int wv   = threadIdx.x >> 6;
    int b    = blockIdx.x * 4 + wv;
    int lane = threadIdx.x & 63;
    int s = lower_bound_seg(seg, b);
    int e = lower_bound_seg(seg, b + 1);
    int cnt = e - s;

    // pass 1: per-row logits (cached in per-wave LDS), running max
    float m = -INFINITY;
    for (int j = 0; j < cnt; ++j) {
        float d = row_logit(P, att, s + j, query[s + j], lane);
        if (j < MAXBAG && lane == 0) scratch[wv][j] = d;
        m = fmaxf(m, d);
    }
    // pass 2: z (all lanes hold full dots -> no reduction needed)
    float z = 0.f;
    for (int j = 0; j < cnt; ++j) {
        float d = (j < MAXBAG) ? scratch[wv][j]
                               : row_logit(P, att, s + j, query[s + j], lane);
        z += expf(d - m);
    }
    float invz = (cnt > 0) ? 1.f / z : 0.f;

    // pass 3: weighted sum of (L1-hot) pooled rows
    float acc[3][4];
#pragma unroll
    for (int jj = 0; jj < 3; ++jj)
#pragma unroll
        for (int c = 0; c < 4; ++c) acc[jj][c] = 0.f;
    for (int j = 0; j < cnt; ++j) {
        float d = (j < MAXBAG) ? scratch[wv][j]
                               : row_logit(P, att, s + j, query[s + j], lane);
        float w = expf(d - m) * invz;
        const ushort4* row = (const ushort4*)(P + (size_t)(s + j) * D_);
#pragma unroll
        for (int jj = 0; jj < 3; ++jj) {
            ushort4 v = row[lane + jj * 64];
            acc[jj][0] += w * bf2f(v.x);
            acc[jj][1] += w * bf2f(v.y);
            acc[jj][2] += w * bf2f(v.z);
            acc[jj][3] += w * bf2f(v.w);
        }
    }
    ushort4* o = (ushort4*)(R + (size_t)b * D_);
#pragma unroll
    for (int jj = 0; jj < 3; ++jj) {
        ushort4 v;
        v.x = f2bf(acc[jj][0]); v.y = f2bf(acc[jj][1]);
        v.z = f2bf(acc[jj][2]); v.w = f2bf(acc[jj][3]);
        o[lane + jj * 64] = v;
    }
}

extern "C" void kernel_launch(void* const* d_in, const int* in_sizes, int n_in,
                              void* d_out, int out_size, void* d_ws, size_t ws_size,
                              hipStream_t stream) {
    const float* h    = (const float*)d_in[0];
    const float* Wfc  = (const float*)d_in[1];
    const float* bfc  = (const float*)d_in[2];
    const float* att  = (const float*)d_in[3];
    const float* Wcls = (const float*)d_in[4];
    const float* bcls = (const float*)d_in[5];
    const int*   query= (const int*)d_in[6];
    const int*   seg  = (const int*)d_in[7];
    float* out = (float*)d_out;

    char* w = (char*)d_ws;
    unsigned short* Wt     = (unsigned short*)w;  w += (size_t)D_ * D_ * 2;
    unsigned short* Wct    = (unsigned short*)w;  w += (size_t)128 * D_ * 2;
    unsigned short* pooled = (unsigned short*)w;  w += (size_t)N_ * D_ * 2;
    unsigned short* repre  = (unsigned short*)w;  // B_*D_*2

    prep_kernel<<<WT_BLK + WCT_BLK, 256, 0, stream>>>(Wfc, Wt, Wcls, Wct);
    gemm_pooled<<<NTILES * (N_ / 128), 256, 0, stream>>>(h, Wt, bfc, pooled);
    bag_kernel <<<B_ / 4, 256, 0, stream>>>(pooled, att, query, seg, repre);
    gemm_cls   <<<B_ / 128, 256, 0, stream>>>(repre, Wct, bcls, out);
}

// Round 6
// 504.869 us; speedup vs baseline: 1.3842x; 1.3842x over previous
//
#include <hip/hip_runtime.h>

#define N_ 65536
#define D_ 768
#define L_ 100
#define B_ 8192
#define MAXBAG 64    // per-wave logit scratch (bags ~Poisson(8), max ~30)

#define A2_BLK (L_ * D_ / 4)   // 19200 blocks, 4 waves each: one (q,d) per wave
#define W2_BLK (D_ / 2)        // 384 blocks: 2 rows of W2 each

// ---- prep: Att2 = att @ W_fc^T, W2 = W_fc @ W_cls, c = att@b_fc, b2 = b_fc@W_cls
__global__ __launch_bounds__(256) void prep_kernel(
    const float* __restrict__ Wfc,  const float* __restrict__ att,
    const float* __restrict__ Wcls, const float* __restrict__ bfc,
    float* __restrict__ Att2, float* __restrict__ W2,
    float* __restrict__ cq,   float* __restrict__ b2)
{
    int bid = blockIdx.x;
    if (bid < A2_BLK) {
        // Att2[q][d] = dot(W_fc row d, att row q) — one wave per (q,d)
        int gw   = bid * 4 + (threadIdx.x >> 6);
        int lane = threadIdx.x & 63;
        int q = gw / D_, d = gw % D_;
        const float4* wr = (const float4*)(Wfc + (size_t)d * D_);
        const float4* ar = (const float4*)(att + (size_t)q * D_);
        float s = 0.f;
#pragma unroll
        for (int jj = 0; jj < 3; ++jj) {
            float4 w4 = wr[lane + jj * 64];
            float4 a4 = ar[lane + jj * 64];
            s += w4.x * a4.x + w4.y * a4.y + w4.z * a4.z + w4.w * a4.w;
        }
#pragma unroll
        for (int off = 32; off > 0; off >>= 1) s += __shfl_xor(s, off, 64);
        if (lane == 0) Att2[(size_t)q * D_ + d] = s;
    } else if (bid < A2_BLK + W2_BLK) {
        // W2[d][l] = dot(W_fc row d, W_cls col l) — 2 d-rows per block
        __shared__ float wf[2 * D_];
        int bb = bid - A2_BLK;
        for (int t = threadIdx.x; t < 2 * D_; t += 256)
            wf[t] = Wfc[(size_t)(bb * 2) * D_ + t];   // rows 2bb,2bb+1 contiguous
        __syncthreads();
        int l  = threadIdx.x & 127;
        int dh = threadIdx.x >> 7;
        if (l < L_) {
            float s = 0.f;
#pragma unroll 4
            for (int j = 0; j < D_; ++j)
                s += wf[dh * D_ + j] * Wcls[j * L_ + l];
            W2[(size_t)(bb * 2 + dh) * L_ + l] = s;
        }
    } else {
        // c[q] = att[q]·b_fc ; b2[l] = b_fc·W_cls[:,l]
        int t = threadIdx.x;
        if (t < L_) {
            float s = 0.f;
#pragma unroll 4
            for (int j = 0; j < D_; ++j) s += att[(size_t)t * D_ + j] * bfc[j];
            cq[t] = s;
        } else if (t < 2 * L_) {
            int l = t - L_;
            float s = 0.f;
#pragma unroll 4
            for (int j = 0; j < D_; ++j) s += bfc[j] * Wcls[j * L_ + l];
            b2[l] = s;
        }
    }
}

__device__ __forceinline__ int lower_bound_seg(const int* __restrict__ seg, int key) {
    int lo = 0, hi = N_;
    while (lo < hi) {
        int mid = (lo + hi) >> 1;
        if (seg[mid] < key) lo = mid + 1; else hi = mid;
    }
    return lo;
}

// full-wave dot: logit_i = Att2[q]·h_i + c[q]; every lane returns the value
__device__ __forceinline__ float row_logit(
    const float* __restrict__ H, const float* __restrict__ Att2,
    const float* __restrict__ cq, int i, int q, int lane)
{
    const float4* hr = (const float4*)(H + (size_t)i * D_);
    const float4* ar = (const float4*)(Att2 + (size_t)q * D_);
    float d = 0.f;
#pragma unroll
    for (int jj = 0; jj < 3; ++jj) {
        float4 v = hr[lane + jj * 64];
        float4 a = ar[lane + jj * 64];
        d += v.x * a.x + v.y * a.y + v.z * a.z + v.w * a.w;
    }
#pragma unroll
    for (int off = 32; off > 0; off >>= 1) d += __shfl_xor(d, off, 64);
    return d + cq[q];   // identical on all 64 lanes
}

// ---- per-bag: logits + softmax + hbar = Σ w_i h_i, one wave per bag ---------
__global__ __launch_bounds__(256) void bag_kernel(
    const float* __restrict__ H, const float* __restrict__ Att2,
    const float* __restrict__ cq, const int* __restrict__ query,
    const int* __restrict__ seg,
    float* __restrict__ hbar, float* __restrict__ sflag)
{
    __shared__ float scratch[4][MAXBAG];
    int wv   = threadIdx.x >> 6;
    int b    = blockIdx.x * 4 + wv;
    int lane = threadIdx.x & 63;
    int s = lower_bound_seg(seg, b);
    int e = lower_bound_seg(seg, b + 1);
    int cnt = e - s;

    // pass 1: logits (cached in per-wave LDS), running max
    float m = -INFINITY;
    for (int j = 0; j < cnt; ++j) {
        float d = row_logit(H, Att2, cq, s + j, query[s + j], lane);
        if (j < MAXBAG && lane == 0) scratch[wv][j] = d;
        m = fmaxf(m, d);
    }
    // pass 2: z (all lanes hold full dots)
    float z = 0.f;
    for (int j = 0; j < cnt; ++j) {
        float d = (j < MAXBAG) ? scratch[wv][j]
                               : row_logit(H, Att2, cq, s + j, query[s + j], lane);
        z += expf(d - m);
    }
    float invz = (cnt > 0) ? 1.f / z : 0.f;

    // pass 3: hbar_b = Σ w_i h_i  (h rows L1/L2-hot from pass 1)
    float acc[3][4];
#pragma unroll
    for (int jj = 0; jj < 3; ++jj)
#pragma unroll
        for (int c = 0; c < 4; ++c) acc[jj][c] = 0.f;
    for (int j = 0; j < cnt; ++j) {
        float d = (j < MAXBAG) ? scratch[wv][j]
                               : row_logit(H, Att2, cq, s + j, query[s + j], lane);
        float w = expf(d - m) * invz;
        const float4* row = (const float4*)(H + (size_t)(s + j) * D_);
#pragma unroll
        for (int jj = 0; jj < 3; ++jj) {
            float4 v = row[lane + jj * 64];
            acc[jj][0] += w * v.x; acc[jj][1] += w * v.y;
            acc[jj][2] += w * v.z; acc[jj][3] += w * v.w;
        }
    }
    float4* o = (float4*)(hbar + (size_t)b * D_);
#pragma unroll
    for (int jj = 0; jj < 3; ++jj)
        o[lane + jj * 64] = make_float4(acc[jj][0], acc[jj][1], acc[jj][2], acc[jj][3]);
    if (lane == 0) sflag[b] = (cnt > 0) ? 1.f : 0.f;
}

// ---- out = hbar @ W2 + sflag*b2 + b_cls  (16 bags / block) ------------------
__global__ __launch_bounds__(128) void cls_kernel(
    const float* __restrict__ hbar, const float* __restrict__ W2,
    const float* __restrict__ b2,   const float* __restrict__ bcls,
    const float* __restrict__ sflag, float* __restrict__ out)
{
    __shared__ float sm[16 * D_];
    int b0 = blockIdx.x * 16;
    int tid = threadIdx.x;
    const float* src = hbar + (size_t)b0 * D_;
    for (int idx = tid; idx < 16 * D_; idx += 128) sm[idx] = src[idx];
    __syncthreads();
    if (tid < L_) {
        float acc[16];
#pragma unroll
        for (int j = 0; j < 16; ++j) acc[j] = 0.f;
        for (int d = 0; d < D_; ++d) {
            float wv = W2[d * L_ + tid];
#pragma unroll
            for (int j = 0; j < 16; ++j) acc[j] += sm[j * D_ + d] * wv;
        }
        float bb = bcls[tid], b2v = b2[tid];
#pragma unroll
        for (int j = 0; j < 16; ++j)
            out[(size_t)(b0 + j) * L_ + tid] = acc[j] + sflag[b0 + j] * b2v + bb;
    }
}

extern "C" void kernel_launch(void* const* d_in, const int* in_sizes, int n_in,
                              void* d_out, int out_size, void* d_ws, size_t ws_size,
                              hipStream_t stream) {
    const float* h    = (const float*)d_in[0];
    const float* Wfc  = (const float*)d_in[1];
    const float* bfc  = (const float*)d_in[2];
    const float* att  = (const float*)d_in[3];
    const float* Wcls = (const float*)d_in[4];
    const float* bcls = (const float*)d_in[5];
    const int*   query= (const int*)d_in[6];
    const int*   seg  = (const int*)d_in[7];
    float* out = (float*)d_out;

    char* w = (char*)d_ws;
    float* Att2  = (float*)w;  w += (size_t)L_ * D_ * 4;
    float* W2    = (float*)w;  w += (size_t)D_ * L_ * 4;
    float* cq    = (float*)w;  w += 128 * 4;
    float* b2    = (float*)w;  w += 128 * 4;
    float* sflag = (float*)w;  w += (size_t)B_ * 4;
    float* hbar  = (float*)w;  // B_*D_*4 = 25 MB

    prep_kernel<<<A2_BLK + W2_BLK + 1, 256, 0, stream>>>(
        Wfc, att, Wcls, bfc, Att2, W2, cq, b2);
    bag_kernel <<<B_ / 4, 256, 0, stream>>>(h, Att2, cq, query, seg, hbar, sflag);
    cls_kernel <<<B_ / 16, 128, 0, stream>>>(hbar, W2, b2, bcls, sflag, out);
}

// Round 7
// 462.594 us; speedup vs baseline: 1.5107x; 1.0914x over previous
//
#include <hip/hip_runtime.h>

#define N_ 65536
#define D_ 768
#define L_ 100
#define B_ 8192

#define A2_BLK (L_ * D_ / 4)   // 19200 blocks, 4 waves each: one (q,d) per wave
#define W2_BLK (D_ / 2)        // 384 blocks: 2 rows of W2 each

// ---- prep: Att2 = att @ W_fc^T, W2 = W_fc @ W_cls, c = att@b_fc, b2 = b_fc@W_cls
__global__ __launch_bounds__(256) void prep_kernel(
    const float* __restrict__ Wfc,  const float* __restrict__ att,
    const float* __restrict__ Wcls, const float* __restrict__ bfc,
    float* __restrict__ Att2, float* __restrict__ W2,
    float* __restrict__ cq,   float* __restrict__ b2)
{
    int bid = blockIdx.x;
    if (bid < A2_BLK) {
        // Att2[q][d] = dot(W_fc row d, att row q) — one wave per (q,d)
        int gw   = bid * 4 + (threadIdx.x >> 6);
        int lane = threadIdx.x & 63;
        int q = gw / D_, d = gw % D_;
        const float4* wr = (const float4*)(Wfc + (size_t)d * D_);
        const float4* ar = (const float4*)(att + (size_t)q * D_);
        float s = 0.f;
#pragma unroll
        for (int jj = 0; jj < 3; ++jj) {
            float4 w4 = wr[lane + jj * 64];
            float4 a4 = ar[lane + jj * 64];
            s += w4.x * a4.x + w4.y * a4.y + w4.z * a4.z + w4.w * a4.w;
        }
#pragma unroll
        for (int off = 32; off > 0; off >>= 1) s += __shfl_xor(s, off, 64);
        if (lane == 0) Att2[(size_t)q * D_ + d] = s;
    } else if (bid < A2_BLK + W2_BLK) {
        // W2[d][l] = dot(W_fc row d, W_cls col l) — 2 d-rows per block
        __shared__ float wf[2 * D_];
        int bb = bid - A2_BLK;
        for (int t = threadIdx.x; t < 2 * D_; t += 256)
            wf[t] = Wfc[(size_t)(bb * 2) * D_ + t];
        __syncthreads();
        int l  = threadIdx.x & 127;
        int dh = threadIdx.x >> 7;
        if (l < L_) {
            float s = 0.f;
#pragma unroll 4
            for (int j = 0; j < D_; ++j)
                s += wf[dh * D_ + j] * Wcls[j * L_ + l];
            W2[(size_t)(bb * 2 + dh) * L_ + l] = s;
        }
    } else {
        // c[q] = att[q]·b_fc ; b2[l] = b_fc·W_cls[:,l]
        int t = threadIdx.x;
        if (t < L_) {
            float s = 0.f;
#pragma unroll 4
            for (int j = 0; j < D_; ++j) s += att[(size_t)t * D_ + j] * bfc[j];
            cq[t] = s;
        } else if (t < 2 * L_) {
            int l = t - L_;
            float s = 0.f;
#pragma unroll 4
            for (int j = 0; j < D_; ++j) s += bfc[j] * Wcls[j * L_ + l];
            b2[l] = s;
        }
    }
}

__device__ __forceinline__ int lower_bound_seg(const int* __restrict__ seg, int key) {
    int lo = 0, hi = N_;
    while (lo < hi) {
        int mid = (lo + hi) >> 1;
        if (seg[mid] < key) lo = mid + 1; else hi = mid;
    }
    return lo;
}

// ---- per-bag: single pass over h, online softmax (flash-style) --------------
// One wave per bag. Lane's share of a row = 12 floats, held in registers
// across {dot -> reduce -> rescale -> accumulate}: h is read exactly ONCE.
__global__ __launch_bounds__(256) void bag_kernel(
    const float* __restrict__ H, const float* __restrict__ Att2,
    const float* __restrict__ cq, const int* __restrict__ query,
    const int* __restrict__ seg,
    float* __restrict__ hbar, float* __restrict__ sflag)
{
    int wv   = threadIdx.x >> 6;
    int b    = blockIdx.x * 4 + wv;
    int lane = threadIdx.x & 63;

    // lanes 0 and 1 binary-search in parallel, broadcast
    int se = 0;
    if (lane < 2) se = lower_bound_seg(seg, b + lane);
    int s = __shfl(se, 0, 64);
    int e = __shfl(se, 1, 64);

    float m = -INFINITY, z = 0.f;
    float acc[12];
#pragma unroll
    for (int j = 0; j < 12; ++j) acc[j] = 0.f;

    for (int i = s; i < e; ++i) {
        const float4* hr = (const float4*)(H + (size_t)i * D_);
        const float4* ar = (const float4*)(Att2 + (size_t)query[i] * D_);
        float4 hv[3];
        float d = 0.f;
#pragma unroll
        for (int jj = 0; jj < 3; ++jj) {
            hv[jj]   = hr[lane + jj * 64];
            float4 a = ar[lane + jj * 64];
            d += hv[jj].x * a.x + hv[jj].y * a.y + hv[jj].z * a.z + hv[jj].w * a.w;
        }
#pragma unroll
        for (int off = 32; off > 0; off >>= 1) d += __shfl_xor(d, off, 64);
        d += cq[query[i]];                       // uniform across wave

        float mn    = fmaxf(m, d);
        float alpha = __expf(m - mn);            // m=-inf on first row -> 0
        float wgt   = __expf(d - mn);
        z = z * alpha + wgt;
#pragma unroll
        for (int jj = 0; jj < 3; ++jj) {
            acc[jj*4+0] = acc[jj*4+0] * alpha + wgt * hv[jj].x;
            acc[jj*4+1] = acc[jj*4+1] * alpha + wgt * hv[jj].y;
            acc[jj*4+2] = acc[jj*4+2] * alpha + wgt * hv[jj].z;
            acc[jj*4+3] = acc[jj*4+3] * alpha + wgt * hv[jj].w;
        }
        m = mn;
    }
    float invz = (e > s) ? 1.f / z : 0.f;

    float4* o = (float4*)(hbar + (size_t)b * D_);
#pragma unroll
    for (int jj = 0; jj < 3; ++jj)
        o[lane + jj * 64] = make_float4(acc[jj*4+0] * invz, acc[jj*4+1] * invz,
                                        acc[jj*4+2] * invz, acc[jj*4+3] * invz);
    if (lane == 0) sflag[b] = (e > s) ? 1.f : 0.f;
}

// ---- out = hbar @ W2 + sflag*b2 + b_cls  (8 bags / block, 256 threads) ------
__global__ __launch_bounds__(256) void cls_kernel(
    const float* __restrict__ hbar, const float* __restrict__ W2,
    const float* __restrict__ b2,   const float* __restrict__ bcls,
    const float* __restrict__ sflag, float* __restrict__ out)
{
    __shared__ float sm[8 * D_];                 // 24 KB
    int b0  = blockIdx.x * 8;
    int tid = threadIdx.x;
    const float4* src = (const float4*)(hbar + (size_t)b0 * D_);
    float4* dst = (float4*)sm;
#pragma unroll
    for (int j = 0; j < 6; ++j) dst[tid + j * 256] = src[tid + j * 256];
    __syncthreads();

    int g = tid >> 7;                            // bag half: 0 -> bags 0..3, 1 -> 4..7
    int l = tid & 127;
    if (l < L_) {
        float acc[4];
#pragma unroll
        for (int j = 0; j < 4; ++j) acc[j] = 0.f;
        const float* smg = sm + g * 4 * D_;
        for (int d = 0; d < D_; ++d) {
            float wv = W2[d * L_ + l];
#pragma unroll
            for (int j = 0; j < 4; ++j) acc[j] += smg[j * D_ + d] * wv;
        }
        float bb = bcls[l], b2v = b2[l];
#pragma unroll
        for (int j = 0; j < 4; ++j) {
            int b = b0 + g * 4 + j;
            out[(size_t)b * L_ + l] = acc[j] + sflag[b] * b2v + bb;
        }
    }
}

extern "C" void kernel_launch(void* const* d_in, const int* in_sizes, int n_in,
                              void* d_out, int out_size, void* d_ws, size_t ws_size,
                              hipStream_t stream) {
    const float* h    = (const float*)d_in[0];
    const float* Wfc  = (const float*)d_in[1];
    const float* bfc  = (const float*)d_in[2];
    const float* att  = (const float*)d_in[3];
    const float* Wcls = (const float*)d_in[4];
    const float* bcls = (const float*)d_in[5];
    const int*   query= (const int*)d_in[6];
    const int*   seg  = (const int*)d_in[7];
    float* out = (float*)d_out;

    char* w = (char*)d_ws;
    float* Att2  = (float*)w;  w += (size_t)L_ * D_ * 4;
    float* W2    = (float*)w;  w += (size_t)D_ * L_ * 4;
    float* cq    = (float*)w;  w += 128 * 4;
    float* b2    = (float*)w;  w += 128 * 4;
    float* sflag = (float*)w;  w += (size_t)B_ * 4;
    float* hbar  = (float*)w;  // B_*D_*4 = 25 MB

    prep_kernel<<<A2_BLK + W2_BLK + 1, 256, 0, stream>>>(
        Wfc, att, Wcls, bfc, Att2, W2, cq, b2);
    bag_kernel <<<B_ / 4, 256, 0, stream>>>(h, Att2, cq, query, seg, hbar, sflag);
    cls_kernel <<<B_ / 8, 256, 0, stream>>>(hbar, W2, b2, bcls, sflag, out);
}